// Round 5
// baseline (3765.648 us; speedup 1.0000x reference)
//
#include <hip/hip_runtime.h>
#include <hip/hip_bf16.h>
#include <stdint.h>

// 2-layer LSTM, B=1024 T=80 E=100 U=512 — persistent-weights cooperative kernel.
// R5: K-loop is barrier-free — A-fragments load DIRECT global->VGPR (16-row x 64B
// gather, compiler-pipelined vmcnt), no LDS staging (R4: 8-way ds_read conflicts
// [4.2e7] + per-slot vmcnt(0) drains). B-frags stay VGPR-resident all 81 phases;
// c-state in registers; relaxed-spin tree grid barrier (R4, proven).

#define T_ 80

using bf16 = __hip_bfloat16;
typedef __attribute__((ext_vector_type(8))) short short8;
typedef __attribute__((ext_vector_type(4))) float f32x4;

__device__ __forceinline__ float sigf(float x) { return 1.f / (1.f + __expf(-x)); }
__device__ __forceinline__ float tanh_f(float x) { return 2.f / (1.f + __expf(-2.f * x)) - 1.f; }

// XP[t][b][e] (e padded to 128), bf16
__global__ void embed_kernel(const int* __restrict__ tokens, const float* __restrict__ emb,
                             bf16* __restrict__ XP) {
  int idx = blockIdx.x * 256 + threadIdx.x;
  int e = idx & 127;
  int bt = idx >> 7;
  int b = bt & 1023;
  int t = bt >> 10;
  if (t >= T_) return;
  int tok = tokens[b * T_ + t];
  float v = (e < 100) ? emb[tok * 100 + e] : 0.f;
  XP[idx] = __float2bfloat16(v);
}

// W [Kreal][2048] fp32 -> WT [2048][Kp] bf16 via LDS tile
__global__ void transpose_kernel(const float* __restrict__ W, bf16* __restrict__ WT,
                                 int Kreal, int Kp) {
  __shared__ float tile[32][33];
  int tn = blockIdx.x * 32;
  int tk = blockIdx.y * 32;
  int lx = threadIdx.x & 31;
  int ly = threadIdx.x >> 5;
#pragma unroll
  for (int r = ly; r < 32; r += 8) {
    int k = tk + r;
    tile[r][lx] = (k < Kreal) ? W[(size_t)k * 2048 + tn + lx] : 0.f;
  }
  __syncthreads();
#pragma unroll
  for (int r = ly; r < 32; r += 8)
    WT[(size_t)(tn + r) * Kp + tk + lx] = __float2bfloat16(tile[lx][r]);
}

struct PP {
  const bf16* XP;
  const bf16* W1T; const bf16* U1T; const bf16* W2T; const bf16* U2T;
  const float* b1; const float* b2;
  bf16* H1; bf16* H2;   // ping-pong pairs, stride 524288 elems
  unsigned* bar;        // [g*16]=group counters, [128]=root, [144]=generation
};

// Tree barrier: relaxed arrivals + relaxed spin; ONE release fence (wbL2) in,
// ONE acquire fence (invL2) out. (R3's acquire-spin = buffer_inv per poll = death.)
__device__ __forceinline__ void grid_barrier(unsigned* bar, int bid, int tid) {
  __syncthreads();  // all waves' H stores drained to L2
  if (tid == 0) {
    __builtin_amdgcn_fence(__ATOMIC_RELEASE, "agent");
    unsigned* grp = bar + (bid & 7) * 16;
    unsigned* root = bar + 128;
    unsigned* gen = bar + 144;
    unsigned g = __hip_atomic_load(gen, __ATOMIC_RELAXED, __HIP_MEMORY_SCOPE_AGENT);
    unsigned a = __hip_atomic_fetch_add(grp, 1u, __ATOMIC_RELAXED, __HIP_MEMORY_SCOPE_AGENT);
    if (a == 63u) {
      __hip_atomic_store(grp, 0u, __ATOMIC_RELAXED, __HIP_MEMORY_SCOPE_AGENT);
      unsigned r = __hip_atomic_fetch_add(root, 1u, __ATOMIC_RELAXED, __HIP_MEMORY_SCOPE_AGENT);
      if (r == 7u) {
        __hip_atomic_store(root, 0u, __ATOMIC_RELAXED, __HIP_MEMORY_SCOPE_AGENT);
        __hip_atomic_store(gen, g + 1u, __ATOMIC_RELEASE, __HIP_MEMORY_SCOPE_AGENT);
      }
    }
    while (__hip_atomic_load(gen, __ATOMIC_RELAXED, __HIP_MEMORY_SCOPE_AGENT) == g)
      __builtin_amdgcn_s_sleep(2);
    __builtin_amdgcn_fence(__ATOMIC_ACQUIRE, "agent");
  }
  __syncthreads();
}

// Wave (ch,kh): 128 rows x 32 cols (gates 2ch,2ch+1 x 16 units), K-chunks ≡ kh (2).
template <bool L1>
__device__ void lstm_run(const PP& P, char* smem, int bid) {
  constexpr int NC0 = L1 ? 4 : 16;     // 32-K chunks from src0
  constexpr int NK = L1 ? 20 : 32;
  constexpr int NS = NK / 2;           // slots per wave (K-parity split)
  constexpr int LD0 = L1 ? 128 : 512;
  const int tid = threadIdx.x;
  const int w = tid >> 6, l = tid & 63, q = l >> 4, m = l & 15;
  const int ch = w & 1, kh = w >> 1;
  const int bm = bid & 7;              // == XCD (L2-locality heuristic)
  const int ug = (bid >> 3) & 31;

  const bf16* Wt = L1 ? P.W1T : P.W2T;
  const bf16* Ut = L1 ? P.U1T : P.U2T;
  const float* bias = L1 ? P.b1 : P.b2;
  bf16* Hpair = L1 ? P.H1 : P.H2;
  const bf16* S0 = L1 ? P.XP : P.H1;

  // persistent B-fragments: BF[slot][ct], gate g=ch*2+ct, chunk c=2*slot+kh
  short8 BF[NS][2];
#pragma unroll
  for (int s = 0; s < NS; ++s) {
    int c = 2 * s + kh;
#pragma unroll
    for (int ct = 0; ct < 2; ++ct) {
      int nr = (ch * 2 + ct) * 512 + ug * 16 + m;
      const bf16* src = (c < NC0) ? (Wt + (size_t)nr * LD0 + c * 32)
                                  : (Ut + (size_t)nr * 512 + (c - NC0) * 32);
      BF[s][ct] = *(const short8*)(src + q * 8);
    }
  }

  float creg[8] = {0, 0, 0, 0, 0, 0, 0, 0};
  float* zs = (float*)smem;  // [128][68] fp32 = 34816 B
  const int uu = tid & 15, rb = tid >> 4;
  const float bi = bias[0 * 512 + ug * 16 + uu];
  const float bff = bias[1 * 512 + ug * 16 + uu];
  const float bgg = bias[2 * 512 + ug * 16 + uu];
  const float boo = bias[3 * 512 + ug * 16 + uu];

  for (int phase = 0; phase <= T_; ++phase) {
    const int t = L1 ? phase : phase - 1;
    const bool active = L1 ? (phase < T_) : (phase >= 1);
    if (active) {
      const bf16* A0 = L1 ? (S0 + (size_t)t * 131072)
                          : (S0 + (size_t)((t + 1) & 1) * 524288);
      const bf16* A1 = Hpair + (size_t)(t & 1) * 524288;
      bf16* Ho = Hpair + (size_t)((t + 1) & 1) * 524288;
      // per-lane A-frag bases: lane (q,m) reads rows bm*128+rt*16+m, k q*8..q*8+8
      const bf16* a0b = A0 + (size_t)(bm * 128 + m) * LD0 + q * 8;
      const bf16* a1b = A1 + (size_t)(bm * 128 + m) * 512 + q * 8;

      f32x4 acc[8][2];
#pragma unroll
      for (int rt = 0; rt < 8; ++rt) {
        acc[rt][0] = f32x4{0.f, 0.f, 0.f, 0.f};
        acc[rt][1] = f32x4{0.f, 0.f, 0.f, 0.f};
      }

#pragma unroll
      for (int s = 0; s < NS; ++s) {
        const int c = 2 * s + kh;
        const bf16* src;
        int rstr;  // 16-row stride in elements
        if (c < NC0) { src = a0b + c * 32; rstr = LD0 * 16; }
        else { src = a1b + (c - NC0) * 32; rstr = 512 * 16; }
        // rt-half-split keeps <=4 frags live -> fits the 256-VGPR cap
#pragma unroll
        for (int h = 0; h < 2; ++h) {
          uint4 av[4];
#pragma unroll
          for (int i = 0; i < 4; ++i)
            av[i] = *(const uint4*)(src + (size_t)(h * 4 + i) * rstr);
#pragma unroll
          for (int i = 0; i < 4; ++i) {
            short8 a = *(short8*)&av[i];
            acc[h * 4 + i][0] =
                __builtin_amdgcn_mfma_f32_16x16x32_bf16(a, BF[s][0], acc[h * 4 + i][0], 0, 0, 0);
            acc[h * 4 + i][1] =
                __builtin_amdgcn_mfma_f32_16x16x32_bf16(a, BF[s][1], acc[h * 4 + i][1], 0, 0, 0);
          }
        }
      }

      // K-parity combine in zs[128][68] (write pattern 2-way aliased = free)
      __syncthreads();
      if (kh == 0) {
#pragma unroll
        for (int rt = 0; rt < 8; ++rt)
#pragma unroll
          for (int ct = 0; ct < 2; ++ct)
#pragma unroll
            for (int r = 0; r < 4; ++r)
              zs[(rt * 16 + q * 4 + r) * 68 + ch * 32 + ct * 16 + m] = acc[rt][ct][r];
      }
      __syncthreads();
      if (kh == 1) {
#pragma unroll
        for (int rt = 0; rt < 8; ++rt)
#pragma unroll
          for (int ct = 0; ct < 2; ++ct)
#pragma unroll
            for (int r = 0; r < 4; ++r)
              zs[(rt * 16 + q * 4 + r) * 68 + ch * 32 + ct * 16 + m] += acc[rt][ct][r];
      }
      __syncthreads();

#pragma unroll
      for (int p = 0; p < 8; ++p) {
        int row = rb + p * 16;
        float zi = zs[row * 68 + 0 + uu] + bi;
        float zf = zs[row * 68 + 16 + uu] + bff;
        float zg = zs[row * 68 + 32 + uu] + bgg;
        float zo = zs[row * 68 + 48 + uu] + boo;
        float c = sigf(zf) * creg[p] + sigf(zi) * tanh_f(zg);
        creg[p] = c;
        Ho[(size_t)(bm * 128 + row) * 512 + ug * 16 + uu] = __float2bfloat16(sigf(zo) * tanh_f(c));
      }
    }
    if (phase < T_) grid_barrier(P.bar, bid, tid);
  }
}

__global__ __launch_bounds__(256, 2) void lstm_persistent(PP P) {
  __shared__ alignas(16) char smem[34816];  // zs[128][68] f32
  const int bid = blockIdx.x;
  if (bid < 256) lstm_run<true>(P, smem, bid);
  else lstm_run<false>(P, smem, bid);
}

// out[b] = sigmoid(h2[b,:] @ Wout + bout)
__global__ void output_kernel(const bf16* __restrict__ H2, const float* __restrict__ Wout,
                              const float* __restrict__ bout, float* __restrict__ out) {
  int w = threadIdx.x >> 6, l = threadIdx.x & 63;
  int row = blockIdx.x * 4 + w;
  const bf16* h = H2 + (size_t)row * 512;
  float s = 0.f;
#pragma unroll
  for (int k = 0; k < 8; ++k) {
    int kk = l + k * 64;
    s += __bfloat162float(h[kk]) * Wout[kk];
  }
#pragma unroll
  for (int off = 32; off > 0; off >>= 1) s += __shfl_down(s, off);
  if (l == 0) out[row] = sigf(s + bout[0]);
}

extern "C" void kernel_launch(void* const* d_in, const int* in_sizes, int n_in,
                              void* d_out, int out_size, void* d_ws, size_t ws_size,
                              hipStream_t stream) {
  const int* tokens = (const int*)d_in[0];
  const float* emb = (const float*)d_in[1];
  const float* W1 = (const float*)d_in[2];
  const float* U1 = (const float*)d_in[3];
  const float* b1 = (const float*)d_in[4];
  const float* W2 = (const float*)d_in[5];
  const float* U2 = (const float*)d_in[6];
  const float* b2 = (const float*)d_in[7];
  const float* Wout = (const float*)d_in[8];
  const float* bout = (const float*)d_in[9];
  float* out = (float*)d_out;
  char* ws = (char*)d_ws;

  const size_t oXP = 0;          // 20971520
  const size_t oW1T = 20971520;  // 524288
  const size_t oU1T = 21495808;  // 2097152
  const size_t oW2T = 23592960;  // 2097152
  const size_t oU2T = 25690112;  // 2097152
  const size_t oH1 = 27787264;   // 2097152 (2 bufs)
  const size_t oH2 = 29884416;   // 2097152
  const size_t oBar = 31981568;  // 1024
  if (ws_size < 31982592) return;

  bf16* XP = (bf16*)(ws + oXP);
  bf16* W1T = (bf16*)(ws + oW1T);
  bf16* U1T = (bf16*)(ws + oU1T);
  bf16* W2T = (bf16*)(ws + oW2T);
  bf16* U2T = (bf16*)(ws + oU2T);
  bf16* H1 = (bf16*)(ws + oH1);
  bf16* H2 = (bf16*)(ws + oH2);
  unsigned* bar = (unsigned*)(ws + oBar);

  hipMemsetAsync(ws + oH1, 0, 1048576, stream);  // H1 buf0
  hipMemsetAsync(ws + oH2, 0, 1048576, stream);  // H2 buf0
  hipMemsetAsync(ws + oBar, 0, 1024, stream);    // barrier state

  embed_kernel<<<40960, 256, 0, stream>>>(tokens, emb, XP);
  transpose_kernel<<<dim3(64, 4), 256, 0, stream>>>(W1, W1T, 100, 128);
  transpose_kernel<<<dim3(64, 16), 256, 0, stream>>>(U1, U1T, 512, 512);
  transpose_kernel<<<dim3(64, 16), 256, 0, stream>>>(W2, W2T, 512, 512);
  transpose_kernel<<<dim3(64, 16), 256, 0, stream>>>(U2, U2T, 512, 512);

  PP P;
  P.XP = XP; P.W1T = W1T; P.U1T = U1T; P.W2T = W2T; P.U2T = U2T;
  P.b1 = b1; P.b2 = b2; P.H1 = H1; P.H2 = H2; P.bar = bar;
  void* args[] = {&P};
  hipLaunchCooperativeKernel((const void*)lstm_persistent, dim3(512), dim3(256),
                             args, 0, stream);

  output_kernel<<<256, 256, 0, stream>>>(H2, Wout, bout, out);
}

// Round 6
// 3226.031 us; speedup vs baseline: 1.1673x; 1.1673x over previous
//
#include <hip/hip_runtime.h>
#include <hip/hip_bf16.h>
#include <stdint.h>

// 2-layer LSTM, B=1024 T=80 E=100 U=512 — persistent cooperative kernel, R6.
// Fix R4/R5's register starvation (VGPR_Count=128 + BF spills -> scratch traffic,
// 221MB WRITE): 256 blocks x 512 thr (1/CU, 256 regs/wave). Waves (ct x kh):
// BW2 64 + BW1 40 + acc 64 regs — all resident, no spill. Both layers per block
// per phase; barrier-free K-loops (plain loads, compiler-pipelined); 4-way
// K-combine via 2 col-major LDS regions; R4's relaxed-tree grid barrier.

#define T_ 80

using bf16 = __hip_bfloat16;
typedef __attribute__((ext_vector_type(8))) short short8;
typedef __attribute__((ext_vector_type(4))) float f32x4;

__device__ __forceinline__ float sigf(float x) { return 1.f / (1.f + __expf(-x)); }
__device__ __forceinline__ float tanh_f(float x) { return 2.f / (1.f + __expf(-2.f * x)) - 1.f; }

// XP[t][b][e] (e padded to 128), bf16
__global__ void embed_kernel(const int* __restrict__ tokens, const float* __restrict__ emb,
                             bf16* __restrict__ XP) {
  int idx = blockIdx.x * 256 + threadIdx.x;
  int e = idx & 127;
  int bt = idx >> 7;
  int b = bt & 1023;
  int t = bt >> 10;
  if (t >= T_) return;
  int tok = tokens[b * T_ + t];
  float v = (e < 100) ? emb[tok * 100 + e] : 0.f;
  XP[idx] = __float2bfloat16(v);
}

// W [Kreal][2048] fp32 -> WT [2048][Kp] bf16 via LDS tile
__global__ void transpose_kernel(const float* __restrict__ W, bf16* __restrict__ WT,
                                 int Kreal, int Kp) {
  __shared__ float tile[32][33];
  int tn = blockIdx.x * 32;
  int tk = blockIdx.y * 32;
  int lx = threadIdx.x & 31;
  int ly = threadIdx.x >> 5;
#pragma unroll
  for (int r = ly; r < 32; r += 8) {
    int k = tk + r;
    tile[r][lx] = (k < Kreal) ? W[(size_t)k * 2048 + tn + lx] : 0.f;
  }
  __syncthreads();
#pragma unroll
  for (int r = ly; r < 32; r += 8)
    WT[(size_t)(tn + r) * Kp + tk + lx] = __float2bfloat16(tile[lx][r]);
}

struct PP {
  const bf16* XP;
  const bf16* W1T; const bf16* U1T; const bf16* W2T; const bf16* U2T;
  const float* b1; const float* b2;
  bf16* H1; bf16* H2;   // ping-pong pairs, stride 524288 elems
  unsigned* bar;        // [g*16] g<8 group counters, [128]=root, [144]=generation
};

// Relaxed-tree grid barrier (R4-proven): relaxed arrivals/spin, ONE release fence
// (wbL2) in, ONE acquire fence (invL2+L1) out. 256 blocks: 8 groups x 32.
__device__ __forceinline__ void grid_barrier(unsigned* bar, int bid, int tid) {
  __syncthreads();
  if (tid == 0) {
    __builtin_amdgcn_fence(__ATOMIC_RELEASE, "agent");
    unsigned* grp = bar + (bid & 7) * 16;
    unsigned* root = bar + 128;
    unsigned* gen = bar + 144;
    unsigned g = __hip_atomic_load(gen, __ATOMIC_RELAXED, __HIP_MEMORY_SCOPE_AGENT);
    unsigned a = __hip_atomic_fetch_add(grp, 1u, __ATOMIC_RELAXED, __HIP_MEMORY_SCOPE_AGENT);
    if (a == 31u) {
      __hip_atomic_store(grp, 0u, __ATOMIC_RELAXED, __HIP_MEMORY_SCOPE_AGENT);
      unsigned r = __hip_atomic_fetch_add(root, 1u, __ATOMIC_RELAXED, __HIP_MEMORY_SCOPE_AGENT);
      if (r == 7u) {
        __hip_atomic_store(root, 0u, __ATOMIC_RELAXED, __HIP_MEMORY_SCOPE_AGENT);
        __hip_atomic_store(gen, g + 1u, __ATOMIC_RELEASE, __HIP_MEMORY_SCOPE_AGENT);
      }
    }
    while (__hip_atomic_load(gen, __ATOMIC_RELAXED, __HIP_MEMORY_SCOPE_AGENT) == g)
      __builtin_amdgcn_s_sleep(2);
    __builtin_amdgcn_fence(__ATOMIC_ACQUIRE, "agent");
  }
  __syncthreads();
}

// One GEMM + K-parity combine. Wave (ct,kh): 128 rows x 32 cols (ct half of 64
// z-cols), K chunks kh*NS..+NS. Result z lands in zsA+zsB (caller sums).
template <int NS, int NC0, int LD0>
__device__ __forceinline__ void gemm_combine(const short8 BW[][2], const bf16* A0,
                                             const bf16* A1, int bm, int ct, int kh,
                                             int q, int m, float (*zsA)[136],
                                             float (*zsB)[136]) {
  f32x4 acc[8][2];
#pragma unroll
  for (int rt = 0; rt < 8; ++rt) {
    acc[rt][0] = f32x4{0.f, 0.f, 0.f, 0.f};
    acc[rt][1] = f32x4{0.f, 0.f, 0.f, 0.f};
  }
#pragma unroll
  for (int s = 0; s < NS; ++s) {
    const int c = kh * NS + s;  // wave-uniform
    const bf16* base;
    size_t ld;
    if (c < NC0) { base = A0 + c * 32; ld = LD0; }
    else { base = A1 + (c - NC0) * 32; ld = 512; }
    const bf16* ab = base + (size_t)(bm * 128 + m) * ld + q * 8;
    uint4 av[8];
#pragma unroll
    for (int rt = 0; rt < 8; ++rt) av[rt] = *(const uint4*)(ab + (size_t)rt * 16 * ld);
#pragma unroll
    for (int rt = 0; rt < 8; ++rt) {
      short8 a = *(short8*)&av[rt];
      acc[rt][0] = __builtin_amdgcn_mfma_f32_16x16x32_bf16(a, BW[s][0], acc[rt][0], 0, 0, 0);
      acc[rt][1] = __builtin_amdgcn_mfma_f32_16x16x32_bf16(a, BW[s][1], acc[rt][1], 0, 0, 0);
    }
  }
  // combine: kh 0,1 -> zsA; kh 2,3 -> zsB. Writers (kh even) then adders (kh odd).
  float(*zs)[136] = (kh >> 1) ? zsB : zsA;
  __syncthreads();
  if ((kh & 1) == 0) {
#pragma unroll
    for (int rt = 0; rt < 8; ++rt)
#pragma unroll
      for (int cg = 0; cg < 2; ++cg)
        *(f32x4*)&zs[ct * 32 + cg * 16 + m][rt * 16 + q * 4] = acc[rt][cg];
  }
  __syncthreads();
  if (kh & 1) {
#pragma unroll
    for (int rt = 0; rt < 8; ++rt)
#pragma unroll
      for (int cg = 0; cg < 2; ++cg) {
        f32x4 v = *(f32x4*)&zs[ct * 32 + cg * 16 + m][rt * 16 + q * 4];
        v += acc[rt][cg];
        *(f32x4*)&zs[ct * 32 + cg * 16 + m][rt * 16 + q * 4] = v;
      }
  }
  __syncthreads();
}

// 256 blocks x 512 threads, 1 block/CU. Block = (bm rows-128, ug units-16), both layers.
__global__ __launch_bounds__(512, 2) void lstm_persistent(PP P) {
  __shared__ float zsA[64][136];  // col-major z halves: [col][row]
  __shared__ float zsB[64][136];
  const int bid = blockIdx.x;
  const int bm = bid & 7, ug = bid >> 3;
  const int tid = threadIdx.x;
  const int w = tid >> 6, l = tid & 63, q = l >> 4, m = l & 15;
  const int ct = w & 1, kh = w >> 1;

  // resident B-fragments. cols = gate-major: col = g*16+unit; wave covers gates
  // {2ct, 2ct+1}. frag (chunk c, cg): weight row N = (ct*2+cg)*512 + ug*16 + m.
  short8 BW1[5][2], BW2[8][2];
  const int Nbase = ug * 16 + m;
#pragma unroll
  for (int s = 0; s < 5; ++s) {
    int c = kh * 5 + s;
#pragma unroll
    for (int cg = 0; cg < 2; ++cg) {
      int N = (ct * 2 + cg) * 512 + Nbase;
      const bf16* src = (c < 4) ? (P.W1T + (size_t)N * 128 + c * 32)
                                : (P.U1T + (size_t)N * 512 + (c - 4) * 32);
      BW1[s][cg] = *(const short8*)(src + q * 8);
    }
  }
#pragma unroll
  for (int s = 0; s < 8; ++s) {
    int c = kh * 8 + s;
#pragma unroll
    for (int cg = 0; cg < 2; ++cg) {
      int N = (ct * 2 + cg) * 512 + Nbase;
      const bf16* src = (c < 16) ? (P.W2T + (size_t)N * 512 + c * 32)
                                 : (P.U2T + (size_t)N * 512 + (c - 16) * 32);
      BW2[s][cg] = *(const short8*)(src + q * 8);
    }
  }

  // epilogue mapping: thread = (unit uu, rows rq*4..+4); c-state in regs
  const int uu = tid & 15, rq = tid >> 4;
  float b1r[4], b2r[4];
#pragma unroll
  for (int g = 0; g < 4; ++g) {
    b1r[g] = P.b1[g * 512 + ug * 16 + uu];
    b2r[g] = P.b2[g * 512 + ug * 16 + uu];
  }
  float c1[4] = {0, 0, 0, 0}, c2[4] = {0, 0, 0, 0};
  const size_t hrow = (size_t)(bm * 128 + rq * 4) * 512 + ug * 16 + uu;

  for (int phase = 0; phase <= T_; ++phase) {
    if (phase < T_) {  // layer1(t=phase): [XP_t | H1[t&1]] -> H1[(t+1)&1]
      const int t = phase;
      const bf16* A0 = P.XP + (size_t)t * 131072;
      const bf16* A1 = P.H1 + (size_t)(t & 1) * 524288;
      bf16* Ho = P.H1 + (size_t)((t + 1) & 1) * 524288;
      gemm_combine<5, 4, 128>(BW1, A0, A1, bm, ct, kh, q, m, zsA, zsB);
      f32x4 zv[4];
#pragma unroll
      for (int g = 0; g < 4; ++g)
        zv[g] = *(f32x4*)&zsA[g * 16 + uu][rq * 4] + *(f32x4*)&zsB[g * 16 + uu][rq * 4];
#pragma unroll
      for (int j = 0; j < 4; ++j) {
        float zi = zv[0][j] + b1r[0];
        float zf = zv[1][j] + b1r[1];
        float zg = zv[2][j] + b1r[2];
        float zo = zv[3][j] + b1r[3];
        float c = sigf(zf) * c1[j] + sigf(zi) * tanh_f(zg);
        c1[j] = c;
        Ho[hrow + (size_t)j * 512] = __float2bfloat16(sigf(zo) * tanh_f(c));
      }
    }
    if (phase >= 1) {  // layer2(t=phase-1): [H1[(t+1)&1] | H2[t&1]] -> H2[(t+1)&1]
      const int t = phase - 1;
      const bf16* A0 = P.H1 + (size_t)((t + 1) & 1) * 524288;
      const bf16* A1 = P.H2 + (size_t)(t & 1) * 524288;
      bf16* Ho = P.H2 + (size_t)((t + 1) & 1) * 524288;
      gemm_combine<8, 16, 512>(BW2, A0, A1, bm, ct, kh, q, m, zsA, zsB);
      f32x4 zv[4];
#pragma unroll
      for (int g = 0; g < 4; ++g)
        zv[g] = *(f32x4*)&zsA[g * 16 + uu][rq * 4] + *(f32x4*)&zsB[g * 16 + uu][rq * 4];
#pragma unroll
      for (int j = 0; j < 4; ++j) {
        float zi = zv[0][j] + b2r[0];
        float zf = zv[1][j] + b2r[1];
        float zg = zv[2][j] + b2r[2];
        float zo = zv[3][j] + b2r[3];
        float c = sigf(zf) * c2[j] + sigf(zi) * tanh_f(zg);
        c2[j] = c;
        Ho[hrow + (size_t)j * 512] = __float2bfloat16(sigf(zo) * tanh_f(c));
      }
    }
    if (phase < T_) grid_barrier(P.bar, bid, tid);
  }
}

// out[b] = sigmoid(h2[b,:] @ Wout + bout)
__global__ void output_kernel(const bf16* __restrict__ H2, const float* __restrict__ Wout,
                              const float* __restrict__ bout, float* __restrict__ out) {
  int w = threadIdx.x >> 6, l = threadIdx.x & 63;
  int row = blockIdx.x * 4 + w;
  const bf16* h = H2 + (size_t)row * 512;
  float s = 0.f;
#pragma unroll
  for (int k = 0; k < 8; ++k) {
    int kk = l + k * 64;
    s += __bfloat162float(h[kk]) * Wout[kk];
  }
#pragma unroll
  for (int off = 32; off > 0; off >>= 1) s += __shfl_down(s, off);
  if (l == 0) out[row] = sigf(s + bout[0]);
}

extern "C" void kernel_launch(void* const* d_in, const int* in_sizes, int n_in,
                              void* d_out, int out_size, void* d_ws, size_t ws_size,
                              hipStream_t stream) {
  const int* tokens = (const int*)d_in[0];
  const float* emb = (const float*)d_in[1];
  const float* W1 = (const float*)d_in[2];
  const float* U1 = (const float*)d_in[3];
  const float* b1 = (const float*)d_in[4];
  const float* W2 = (const float*)d_in[5];
  const float* U2 = (const float*)d_in[6];
  const float* b2 = (const float*)d_in[7];
  const float* Wout = (const float*)d_in[8];
  const float* bout = (const float*)d_in[9];
  float* out = (float*)d_out;
  char* ws = (char*)d_ws;

  const size_t oXP = 0;          // 20971520
  const size_t oW1T = 20971520;  // 524288
  const size_t oU1T = 21495808;  // 2097152
  const size_t oW2T = 23592960;  // 2097152
  const size_t oU2T = 25690112;  // 2097152
  const size_t oH1 = 27787264;   // 2097152 (2 bufs)
  const size_t oH2 = 29884416;   // 2097152
  const size_t oBar = 31981568;  // 1024
  if (ws_size < 31982592) return;

  bf16* XP = (bf16*)(ws + oXP);
  bf16* W1T = (bf16*)(ws + oW1T);
  bf16* U1T = (bf16*)(ws + oU1T);
  bf16* W2T = (bf16*)(ws + oW2T);
  bf16* U2T = (bf16*)(ws + oU2T);
  bf16* H1 = (bf16*)(ws + oH1);
  bf16* H2 = (bf16*)(ws + oH2);
  unsigned* bar = (unsigned*)(ws + oBar);

  hipMemsetAsync(ws + oH1, 0, 1048576, stream);  // H1 buf0
  hipMemsetAsync(ws + oH2, 0, 1048576, stream);  // H2 buf0
  hipMemsetAsync(ws + oBar, 0, 1024, stream);    // barrier state

  embed_kernel<<<40960, 256, 0, stream>>>(tokens, emb, XP);
  transpose_kernel<<<dim3(64, 4), 256, 0, stream>>>(W1, W1T, 100, 128);
  transpose_kernel<<<dim3(64, 16), 256, 0, stream>>>(U1, U1T, 512, 512);
  transpose_kernel<<<dim3(64, 16), 256, 0, stream>>>(W2, W2T, 512, 512);
  transpose_kernel<<<dim3(64, 16), 256, 0, stream>>>(U2, U2T, 512, 512);

  PP P;
  P.XP = XP; P.W1T = W1T; P.U1T = U1T; P.W2T = W2T; P.U2T = U2T;
  P.b1 = b1; P.b2 = b2; P.H1 = H1; P.H2 = H2; P.bar = bar;
  void* args[] = {&P};
  hipLaunchCooperativeKernel((const void*)lstm_persistent, dim3(256), dim3(512),
                             args, 0, stream);

  output_kernel<<<256, 256, 0, stream>>>(H2, Wout, bout, out);
}

// Round 7
// 2405.818 us; speedup vs baseline: 1.5652x; 1.3409x over previous
//
#include <hip/hip_runtime.h>
#include <hip/hip_bf16.h>
#include <stdint.h>

// 2-layer LSTM, B=1024 T=80 E=100 U=512 — persistent cooperative kernel, R7.
// Weights LDS-RESIDENT (132KB of the 160KB/CU; R4-6's weights-in-VGPR spilled at
// VGPR_Count=128). 256 blocks x 512 thr, 1 block/CU. Split grid: bid<128 L1(t),
// else L2(t-1) — race-free 1-barrier/phase pipeline (R6 intra-phase race removed).
// Block 256 rows x 64 cols (16 units x 4 gates): in-register gate epilogue,
// c-state in regs. A-frags direct global->VGPR in a barrier-free unrolled K-loop.
// Weight LDS stride 2112B -> b128 B-frag reads hit all 32 banks (conflict-free).

#define T_ 80

using bf16 = __hip_bfloat16;
typedef __attribute__((ext_vector_type(8))) short short8;
typedef __attribute__((ext_vector_type(4))) float f32x4;

__device__ __forceinline__ float sigf(float x) { return 1.f / (1.f + __expf(-x)); }
__device__ __forceinline__ float tanh_f(float x) { return 2.f / (1.f + __expf(-2.f * x)) - 1.f; }

// XP[t][b][e] (e padded to 128), bf16
__global__ void embed_kernel(const int* __restrict__ tokens, const float* __restrict__ emb,
                             bf16* __restrict__ XP) {
  int idx = blockIdx.x * 256 + threadIdx.x;
  int e = idx & 127;
  int bt = idx >> 7;
  int b = bt & 1023;
  int t = bt >> 10;
  if (t >= T_) return;
  int tok = tokens[b * T_ + t];
  float v = (e < 100) ? emb[tok * 100 + e] : 0.f;
  XP[idx] = __float2bfloat16(v);
}

// W [Kreal][2048] fp32 -> WT [2048][Kp] bf16 via LDS tile
__global__ void transpose_kernel(const float* __restrict__ W, bf16* __restrict__ WT,
                                 int Kreal, int Kp) {
  __shared__ float tile[32][33];
  int tn = blockIdx.x * 32;
  int tk = blockIdx.y * 32;
  int lx = threadIdx.x & 31;
  int ly = threadIdx.x >> 5;
#pragma unroll
  for (int r = ly; r < 32; r += 8) {
    int k = tk + r;
    tile[r][lx] = (k < Kreal) ? W[(size_t)k * 2048 + tn + lx] : 0.f;
  }
  __syncthreads();
#pragma unroll
  for (int r = ly; r < 32; r += 8)
    WT[(size_t)(tn + r) * Kp + tk + lx] = __float2bfloat16(tile[lx][r]);
}

struct PP {
  const bf16* XP;
  const bf16* W1T; const bf16* U1T; const bf16* W2T; const bf16* U2T;
  const float* b1; const float* b2;
  bf16* H1; bf16* H2;   // ping-pong pairs, stride 524288 elems
  unsigned* bar;        // [g*16] g<8 group counters, [128]=root, [144]=generation
};

// Relaxed-tree grid barrier (R4-proven): relaxed arrivals/spin, ONE release fence
// (wbL2) in, ONE acquire fence (invL1+L2) out. 256 blocks: 8 groups x 32.
__device__ __forceinline__ void grid_barrier(unsigned* bar, int bid, int tid) {
  __syncthreads();
  if (tid == 0) {
    __builtin_amdgcn_fence(__ATOMIC_RELEASE, "agent");
    unsigned* grp = bar + (bid & 7) * 16;
    unsigned* root = bar + 128;
    unsigned* gen = bar + 144;
    unsigned g = __hip_atomic_load(gen, __ATOMIC_RELAXED, __HIP_MEMORY_SCOPE_AGENT);
    unsigned a = __hip_atomic_fetch_add(grp, 1u, __ATOMIC_RELAXED, __HIP_MEMORY_SCOPE_AGENT);
    if (a == 31u) {
      __hip_atomic_store(grp, 0u, __ATOMIC_RELAXED, __HIP_MEMORY_SCOPE_AGENT);
      unsigned r = __hip_atomic_fetch_add(root, 1u, __ATOMIC_RELAXED, __HIP_MEMORY_SCOPE_AGENT);
      if (r == 7u) {
        __hip_atomic_store(root, 0u, __ATOMIC_RELAXED, __HIP_MEMORY_SCOPE_AGENT);
        __hip_atomic_store(gen, g + 1u, __ATOMIC_RELEASE, __HIP_MEMORY_SCOPE_AGENT);
      }
    }
    while (__hip_atomic_load(gen, __ATOMIC_RELAXED, __HIP_MEMORY_SCOPE_AGENT) == g)
      __builtin_amdgcn_s_sleep(4);
    __builtin_amdgcn_fence(__ATOMIC_ACQUIRE, "agent");
  }
  __syncthreads();
}

#define WSTRIDE 2112  // bytes per weight col in LDS; 2112/4=528 dw == 16 mod 32

// IS_L1: z = [XP_t | H1] @ [W1;U1], NC0=4, NK=20. else: z = [H1' | H2] @ [W2;U2],
// NC0=16, NK=32. Block: rows bm*256..+256, cols = 4 gates x units ug*16..+16.
// Wave w (0..7): rows +w*32..+32. Lane (q,m): A rows +m/+m+16, k q*8.
template <bool IS_L1>
__device__ void lstm_run(const PP& P, char* sW, int lbid, int bid) {
  constexpr int NC0 = IS_L1 ? 4 : 16;
  constexpr int NK = IS_L1 ? 20 : 32;
  constexpr int LD0 = IS_L1 ? 128 : 512;
  const int tid = threadIdx.x;
  const int w = tid >> 6, l = tid & 63, q = l >> 4, m = l & 15;
  const int bm = lbid & 3, ug = lbid >> 2;

  // ---- preload weights into LDS (once): col cb holds N=(cb>>4)*512+ug*16+(cb&15),
  // 16B-unit u at cb*WSTRIDE + u*16  (u = c*4 + q) ----
  {
    const int cb = tid >> 3, kq = tid & 7;
    const int N = (cb >> 4) * 512 + ug * 16 + (cb & 15);
    const bf16* w0 = (IS_L1 ? P.W1T : P.W2T) + (size_t)N * LD0;
    const bf16* u0 = (IS_L1 ? P.U1T : P.U2T) + (size_t)N * 512;
    constexpr int NU = NK * 4;       // 16B units per col
    constexpr int C0U = NC0 * 4;     // units from W-part
#pragma unroll
    for (int i = 0; i < NU / 8; ++i) {
      int u = i * 8 + kq;
      const bf16* src = (u < C0U) ? (w0 + u * 8) : (u0 + (u - C0U) * 8);
      *(uint4*)(sW + cb * WSTRIDE + u * 16) = *(const uint4*)src;
    }
  }
  __syncthreads();

  // per-lane LDS base for B-frags of the 4 gate-tiles
  int ldsb[4];
#pragma unroll
  for (int ct = 0; ct < 4; ++ct) ldsb[ct] = (ct * 16 + m) * WSTRIDE + q * 16;

  const float* bias = IS_L1 ? P.b1 : P.b2;
  bf16* Hpair = IS_L1 ? P.H1 : P.H2;
  float bz[4];
#pragma unroll
  for (int g = 0; g < 4; ++g) bz[g] = bias[g * 512 + ug * 16 + m];

  float creg[2][4] = {{0, 0, 0, 0}, {0, 0, 0, 0}};
  const int row0 = bm * 256 + w * 32 + m;

  for (int phase = 0; phase <= T_; ++phase) {
    const int t = IS_L1 ? phase : phase - 1;
    const bool active = IS_L1 ? (phase < T_) : (phase >= 1);
    if (active) {
      const bf16* A0 = IS_L1 ? (P.XP + (size_t)t * 131072)
                             : (P.H1 + (size_t)((t + 1) & 1) * 524288);
      const bf16* A1 = Hpair + (size_t)(t & 1) * 524288;
      bf16* Ho = Hpair + (size_t)((t + 1) & 1) * 524288;
      const bf16* pa0 = A0 + (size_t)row0 * LD0 + q * 8;
      const bf16* pa1 = A1 + (size_t)row0 * 512 + q * 8;

      f32x4 acc[2][4];
#pragma unroll
      for (int rt = 0; rt < 2; ++rt)
#pragma unroll
        for (int ct = 0; ct < 4; ++ct) acc[rt][ct] = f32x4{0.f, 0.f, 0.f, 0.f};

#pragma unroll
      for (int c = 0; c < NK; ++c) {
        uint4 a0v, a1v;
        if (c < NC0) {
          a0v = *(const uint4*)(pa0 + c * 32);
          a1v = *(const uint4*)(pa0 + c * 32 + 16 * LD0);
        } else {
          a0v = *(const uint4*)(pa1 + (c - NC0) * 32);
          a1v = *(const uint4*)(pa1 + (c - NC0) * 32 + 16 * 512);
        }
        short8 a0 = *(short8*)&a0v;
        short8 a1 = *(short8*)&a1v;
#pragma unroll
        for (int ct = 0; ct < 4; ++ct) {
          short8 bf = *(const short8*)(sW + ldsb[ct] + c * 64);
          acc[0][ct] = __builtin_amdgcn_mfma_f32_16x16x32_bf16(a0, bf, acc[0][ct], 0, 0, 0);
          acc[1][ct] = __builtin_amdgcn_mfma_f32_16x16x32_bf16(a1, bf, acc[1][ct], 0, 0, 0);
        }
      }

      // in-register epilogue: lane (q,m) owns rows w*32+rt*16+q*4+r, unit ug*16+m,
      // all 4 gates (ct). C/D map: row=q*4+reg, col=m.
#pragma unroll
      for (int rt = 0; rt < 2; ++rt)
#pragma unroll
        for (int r = 0; r < 4; ++r) {
          const int row = bm * 256 + w * 32 + rt * 16 + q * 4 + r;
          float zi = acc[rt][0][r] + bz[0];
          float zf = acc[rt][1][r] + bz[1];
          float zg = acc[rt][2][r] + bz[2];
          float zo = acc[rt][3][r] + bz[3];
          float c = sigf(zf) * creg[rt][r] + sigf(zi) * tanh_f(zg);
          creg[rt][r] = c;
          Ho[(size_t)row * 512 + ug * 16 + m] = __float2bfloat16(sigf(zo) * tanh_f(c));
        }
    }
    if (phase < T_) grid_barrier(P.bar, bid, tid);
  }
}

__global__ __launch_bounds__(512, 2) void lstm_persistent(PP P) {
  __shared__ alignas(16) char sW[64 * WSTRIDE];  // 135168 B resident weights
  const int bid = blockIdx.x;
  if (bid < 128) lstm_run<true>(P, sW, bid, bid);
  else lstm_run<false>(P, sW, bid - 128, bid);
}

// out[b] = sigmoid(h2[b,:] @ Wout + bout)
__global__ void output_kernel(const bf16* __restrict__ H2, const float* __restrict__ Wout,
                              const float* __restrict__ bout, float* __restrict__ out) {
  int w = threadIdx.x >> 6, l = threadIdx.x & 63;
  int row = blockIdx.x * 4 + w;
  const bf16* h = H2 + (size_t)row * 512;
  float s = 0.f;
#pragma unroll
  for (int k = 0; k < 8; ++k) {
    int kk = l + k * 64;
    s += __bfloat162float(h[kk]) * Wout[kk];
  }
#pragma unroll
  for (int off = 32; off > 0; off >>= 1) s += __shfl_down(s, off);
  if (l == 0) out[row] = sigf(s + bout[0]);
}

extern "C" void kernel_launch(void* const* d_in, const int* in_sizes, int n_in,
                              void* d_out, int out_size, void* d_ws, size_t ws_size,
                              hipStream_t stream) {
  const int* tokens = (const int*)d_in[0];
  const float* emb = (const float*)d_in[1];
  const float* W1 = (const float*)d_in[2];
  const float* U1 = (const float*)d_in[3];
  const float* b1 = (const float*)d_in[4];
  const float* W2 = (const float*)d_in[5];
  const float* U2 = (const float*)d_in[6];
  const float* b2 = (const float*)d_in[7];
  const float* Wout = (const float*)d_in[8];
  const float* bout = (const float*)d_in[9];
  float* out = (float*)d_out;
  char* ws = (char*)d_ws;

  const size_t oXP = 0;          // 20971520
  const size_t oW1T = 20971520;  // 524288
  const size_t oU1T = 21495808;  // 2097152
  const size_t oW2T = 23592960;  // 2097152
  const size_t oU2T = 25690112;  // 2097152
  const size_t oH1 = 27787264;   // 2097152 (2 bufs)
  const size_t oH2 = 29884416;   // 2097152
  const size_t oBar = 31981568;  // 1024
  if (ws_size < 31982592) return;

  bf16* XP = (bf16*)(ws + oXP);
  bf16* W1T = (bf16*)(ws + oW1T);
  bf16* U1T = (bf16*)(ws + oU1T);
  bf16* W2T = (bf16*)(ws + oW2T);
  bf16* U2T = (bf16*)(ws + oU2T);
  bf16* H1 = (bf16*)(ws + oH1);
  bf16* H2 = (bf16*)(ws + oH2);
  unsigned* bar = (unsigned*)(ws + oBar);

  hipMemsetAsync(ws + oH1, 0, 1048576, stream);  // H1 buf0
  hipMemsetAsync(ws + oH2, 0, 1048576, stream);  // H2 buf0
  hipMemsetAsync(ws + oBar, 0, 1024, stream);    // barrier state

  embed_kernel<<<40960, 256, 0, stream>>>(tokens, emb, XP);
  transpose_kernel<<<dim3(64, 4), 256, 0, stream>>>(W1, W1T, 100, 128);
  transpose_kernel<<<dim3(64, 16), 256, 0, stream>>>(U1, U1T, 512, 512);
  transpose_kernel<<<dim3(64, 16), 256, 0, stream>>>(W2, W2T, 512, 512);
  transpose_kernel<<<dim3(64, 16), 256, 0, stream>>>(U2, U2T, 512, 512);

  PP P;
  P.XP = XP; P.W1T = W1T; P.U1T = U1T; P.W2T = W2T; P.U2T = U2T;
  P.b1 = b1; P.b2 = b2; P.H1 = H1; P.H2 = H2; P.bar = bar;
  void* args[] = {&P};
  hipLaunchCooperativeKernel((const void*)lstm_persistent, dim3(256), dim3(512),
                             args, 0, stream);

  output_kernel<<<256, 256, 0, stream>>>(H2, Wout, bout, out);
}